// Round 2
// baseline (305.888 us; speedup 1.0000x reference)
//
#include <hip/hip_runtime.h>
#include <stdint.h>

// ReconBlock: 3-axis 3-tap submanifold conv (gathered neighbors) + BN(inference)
// + sigmoid per branch, branches summed, gated by input features.
//
// R5: prep+cvt fused into one launch (cvt at 16 floats/thread); recon TPW=5
// (fewer wave prologues, 3125 blocks); nontemporal index loads (read-once,
// keep L2/L3 for fb/feat gather windows). Core recon structure unchanged from
// R4: bf16 feature cache gathers straight into MFMA A-fragments, double-
// buffered gather pipeline, LDS weights, zero-row cndmask for invalid
// neighbors, XCD-aware block swizzle. Legacy fallback when ws is small.

typedef __attribute__((ext_vector_type(8))) __bf16 bf16x8;
typedef __attribute__((ext_vector_type(8))) unsigned short u16x8;
typedef __attribute__((ext_vector_type(4))) float f32x4;
typedef __attribute__((ext_vector_type(2))) float f32x2;

constexpr int NVOX    = 1000000;
constexpr int NTILES  = NVOX / 16;                  // 62500
constexpr int WPB     = 4;                          // waves per block
constexpr float LOG2E = 1.4426950408889634f;

// ---- fast path geometry (bf16 feature cache) ----
constexpr int TPWF     = 5;                         // tiles per wave
constexpr int NWAVESF  = NTILES / TPWF;             // 12500 (exact)
constexpr int NBLOCKSF = NWAVESF / WPB;             // 3125 (exact)

// ---- legacy path geometry ----
constexpr int TPW2     = 2;
constexpr int NWAVES2  = (NTILES + TPW2 - 1) / TPW2;   // 31250
constexpr int NBLOCKS2 = (NWAVES2 + WPB - 1) / WPB;    // 7813

// ws layout (fast): [fb bf16 64e6 B][wsW 18432][wsA 384][wsB 384][zeros 128]
// ws layout (legacy): [wsW 18432][wsA 384][wsB 384]
constexpr int    WS_WELEMS = 18 * 64 * 8;           // 9216 bf16 elems
constexpr size_t FB_BYTES  = (size_t)NVOX * 64;     // 64,000,000
constexpr unsigned ZOFF    = (unsigned)(FB_BYTES + 18432 + 768); // zero row
constexpr size_t WS_NEED   = FB_BYTES + 18432 + 768 + 128;

// fused prep: first CVT_THREADS threads convert features (16 floats each),
// the tail does weight-fragment / BN-constant / zero-row prep.
constexpr int CVT_THREADS = NVOX * 32 / 16;         // 2,000,000
constexpr int PREP_TAIL   = WS_WELEMS + 96 + 32;    // 9344
constexpr int PREPALL_BLK = (CVT_THREADS + PREP_TAIL + 255) / 256; // 7849

__device__ __forceinline__ unsigned pack_bf(float a, float b) {
    union { float f; unsigned u; } ca, cb; ca.f = a; cb.f = b;
    // d = hi16(a+0x8000) | hi16(b+0x8000)<<16  (one v_perm)
    return __builtin_amdgcn_perm(cb.u + 0x8000u, ca.u + 0x8000u, 0x07060302u);
}

__device__ __forceinline__ void prep_tail_work(
    int t, const float* __restrict__ Wt,
    const float* __restrict__ gma, const float* __restrict__ bta,
    const float* __restrict__ mea, const float* __restrict__ var,
    unsigned short* __restrict__ wsW, float* __restrict__ wsA,
    float* __restrict__ wsB, float* __restrict__ wsZ)
{
    if (t < WS_WELEMS) {
        int f    = t >> 9;            // fragment id = (br*3+tap)*2+h
        int rem  = t & 511;
        int lane = rem >> 3;
        int j    = rem & 7;
        int br = f / 6, tap = (f >> 1) % 3, h = f & 1;
        int n = lane & 15, quad = lane >> 4;
        // B[k=quad*8+j][col]; col interleave: half h = original channel 2n+h
        float w = Wt[((br * 3 + tap) * 32 + quad * 8 + j) * 32 + 2 * n + h];
        union { float f; unsigned u; } c; c.f = w;
        wsW[(f * 64 + lane) * 8 + j] = (unsigned short)((c.u + 0x8000u) >> 16);
    } else if (t < WS_WELEMS + 96) {
        int i = t - WS_WELEMS;        // br*32 + c
        float s = gma[i] * __frsqrt_rn(var[i] + 1e-5f);
        wsA[i] = -s * LOG2E;
        wsB[i] = (mea[i] * s - bta[i]) * LOG2E;
    } else if (wsZ != nullptr && t < WS_WELEMS + 96 + 32) {
        wsZ[t - WS_WELEMS - 96] = 0.0f;
    }
}

// fused: feature fp32->bf16 conversion (same +0x8000 rounding as the MFMA
// fragment packing, numerics identical to R3/R4) + weight/BN/zero prep.
__global__ __launch_bounds__(256) void prep_all(
    const float* __restrict__ feat, unsigned short* __restrict__ fb,
    const float* __restrict__ Wt,
    const float* __restrict__ gma, const float* __restrict__ bta,
    const float* __restrict__ mea, const float* __restrict__ var,
    unsigned short* __restrict__ wsW, float* __restrict__ wsA,
    float* __restrict__ wsB, float* __restrict__ wsZ)
{
    int tid = blockIdx.x * 256 + threadIdx.x;
    if (tid < CVT_THREADS) {
        const f32x4* p = (const f32x4*)(feat + (size_t)tid * 16);
        f32x4 v0 = p[0], v1 = p[1], v2 = p[2], v3 = p[3];
        union { unsigned u[8]; u16x8 v[2]; } r;
        r.u[0] = pack_bf(v0[0], v0[1]); r.u[1] = pack_bf(v0[2], v0[3]);
        r.u[2] = pack_bf(v1[0], v1[1]); r.u[3] = pack_bf(v1[2], v1[3]);
        r.u[4] = pack_bf(v2[0], v2[1]); r.u[5] = pack_bf(v2[2], v2[3]);
        r.u[6] = pack_bf(v3[0], v3[1]); r.u[7] = pack_bf(v3[2], v3[3]);
        u16x8* q = (u16x8*)(fb + (size_t)tid * 16);
        q[0] = r.v[0]; q[1] = r.v[1];
    } else {
        prep_tail_work(tid - CVT_THREADS, Wt, gma, bta, mea, var,
                       wsW, wsA, wsB, wsZ);
    }
}

// legacy-path prep (no feature cache)
__global__ __launch_bounds__(256) void prep_kernel(
    const float* __restrict__ Wt,
    const float* __restrict__ gma, const float* __restrict__ bta,
    const float* __restrict__ mea, const float* __restrict__ var,
    unsigned short* __restrict__ wsW, float* __restrict__ wsA,
    float* __restrict__ wsB)
{
    int tid = blockIdx.x * 256 + threadIdx.x;
    prep_tail_work(tid, Wt, gma, bta, mea, var, wsW, wsA, wsB, nullptr);
}

__device__ __forceinline__ bf16x8 cvt_frag(f32x4 lo, f32x4 hi) {
    union { unsigned u[4]; bf16x8 v; } r;
    r.u[0] = pack_bf(lo[0], lo[1]); r.u[1] = pack_bf(lo[2], lo[3]);
    r.u[2] = pack_bf(hi[0], hi[1]); r.u[3] = pack_bf(hi[2], hi[3]);
    return r.v;
}

__device__ __forceinline__ f32x4 mfma16(u16x8 a, bf16x8 b, f32x4 c) {
    return __builtin_amdgcn_mfma_f32_16x16x32_bf16(
        __builtin_bit_cast(bf16x8, a), b, c, 0, 0, 0);
}

// ------------------------------ fast path ------------------------------
__global__ __launch_bounds__(256) void recon_bf16(
    const float* __restrict__ feat,   // [N][32] fp32 (gate only)
    const int*   __restrict__ nprev,  // [3][N]
    const int*   __restrict__ nnext,  // [3][N]
    const char*  __restrict__ fbc,    // ws base: bf16 features at offset 0
    const unsigned short* __restrict__ wsW,
    const float* __restrict__ wsA,
    const float* __restrict__ wsB,
    float*       __restrict__ out)    // [N][32]
{
    __shared__ unsigned short smem[WS_WELEMS];     // 18 KB weight fragments
    {
        const u16x8* s = (const u16x8*)wsW;
        u16x8* d = (u16x8*)smem;
        #pragma unroll
        for (int i = 0; i < 5; ++i) {
            int k = (int)threadIdx.x + i * 256;
            if (k < 18 * 64) d[k] = s[k];
        }
    }
    __syncthreads();

    const int lane = threadIdx.x & 63;
    const int n    = lane & 15;       // lane owns out channels 2n, 2n+1
    const int quad = lane >> 4;
    const unsigned qo = (unsigned)quad * 16u;

    // XCD-aware swizzle: contiguous 1/8th of voxel range per XCD
    int b   = blockIdx.x;
    int per = NBLOCKSF / 8;
    int bs  = (b < per * 8) ? ((b & 7) * per + (b >> 3)) : b;
    int wv  = bs * WPB + (threadIdx.x >> 6);
    if (wv >= NWAVESF) return;
    const int t0 = wv * TPWF;

    // folded BN consts for this lane's channels (2n, 2n+1)
    f32x2 A_[3], B_[3];
    #pragma unroll
    for (int br = 0; br < 3; ++br) {
        A_[br] = *(const f32x2*)(wsA + br * 32 + 2 * n);
        B_[br] = *(const f32x2*)(wsB + br * 32 + 2 * n);
    }

    // opaque per-tile LDS byte offset (defeats LICM of weight ds_reads)
    unsigned lbase = (unsigned)lane * 16u;

    // neighbor indices, 2-deep (nontemporal: strictly read-once streams)
    int idxP[2][3], idxN[2][3];
    {
        int r0 = t0 * 16 + n;
        #pragma unroll
        for (int a = 0; a < 3; ++a) {
            idxP[0][a] = __builtin_nontemporal_load(nprev + a * NVOX + r0);
            idxN[0][a] = __builtin_nontemporal_load(nnext + a * NVOX + r0);
            idxP[1][a] = __builtin_nontemporal_load(nprev + a * NVOX + r0 + 16);
            idxN[1][a] = __builtin_nontemporal_load(nnext + a * NVOX + r0 + 16);
        }
    }

    // gather double buffer: [0]=self, [1..3]=prev a, [4..6]=next a
    u16x8 G[2][7];
    {
        int row0 = t0 * 16 + n;
        G[0][0] = *(const u16x8*)(fbc + (unsigned)row0 * 64u + qo);
        #pragma unroll
        for (int a = 0; a < 3; ++a) {
            unsigned op = idxP[0][a] >= 0 ? (unsigned)idxP[0][a] * 64u : ZOFF;
            unsigned on = idxN[0][a] >= 0 ? (unsigned)idxN[0][a] * 64u : ZOFF;
            G[0][1 + a] = *(const u16x8*)(fbc + op + qo);
            G[0][4 + a] = *(const u16x8*)(fbc + on + qo);
        }
    }

    #pragma unroll
    for (int tt = 0; tt < TPWF; ++tt) {
        const int cur  = tt & 1;
        const int nxt  = cur ^ 1;
        const int base = (t0 + tt) * 16;

        // gate loads early (fp32, read-once -> nontemporal; hidden under MFMA)
        f32x2 fv[4];
        #pragma unroll
        for (int r = 0; r < 4; ++r)
            fv[r] = __builtin_nontemporal_load(
                (const f32x2*)(feat + (base + quad * 4 + r) * 32 + 2 * n));

        // issue next tile's gathers: in flight under this tile's compute
        if (tt + 1 < TPWF) {
            int rown = base + 16 + n;
            G[nxt][0] = *(const u16x8*)(fbc + (unsigned)rown * 64u + qo);
            #pragma unroll
            for (int a = 0; a < 3; ++a) {
                unsigned op = idxP[nxt][a] >= 0 ? (unsigned)idxP[nxt][a] * 64u : ZOFF;
                unsigned on = idxN[nxt][a] >= 0 ? (unsigned)idxN[nxt][a] * 64u : ZOFF;
                G[nxt][1 + a] = *(const u16x8*)(fbc + op + qo);
                G[nxt][4 + a] = *(const u16x8*)(fbc + on + qo);
            }
        }
        // prefetch indices two tiles ahead into the slot just freed
        if (tt + 2 < TPWF) {
            int r2 = base + 32 + n;
            #pragma unroll
            for (int a = 0; a < 3; ++a) {
                idxP[cur][a] = __builtin_nontemporal_load(nprev + a * NVOX + r2);
                idxN[cur][a] = __builtin_nontemporal_load(nnext + a * NVOX + r2);
            }
        }

        asm volatile("" : "+v"(lbase));            // loop-variant LDS base
        const char* sb = (const char*)smem + lbase;

        f32x4 acc0 = {0.f, 0.f, 0.f, 0.f}, acc1 = {0.f, 0.f, 0.f, 0.f};
        #pragma unroll
        for (int br = 0; br < 3; ++br) {
            bf16x8 w0 = *(const bf16x8*)(sb + (br * 6 + 0) * 1024);
            bf16x8 w1 = *(const bf16x8*)(sb + (br * 6 + 1) * 1024);
            bf16x8 w2 = *(const bf16x8*)(sb + (br * 6 + 2) * 1024);
            bf16x8 w3 = *(const bf16x8*)(sb + (br * 6 + 3) * 1024);
            bf16x8 w4 = *(const bf16x8*)(sb + (br * 6 + 4) * 1024);
            bf16x8 w5 = *(const bf16x8*)(sb + (br * 6 + 5) * 1024);
            f32x4 c0 = {0.f, 0.f, 0.f, 0.f}, c1 = {0.f, 0.f, 0.f, 0.f};
            c0 = mfma16(G[cur][1 + br], w0, c0);
            c1 = mfma16(G[cur][1 + br], w1, c1);
            c0 = mfma16(G[cur][0],      w2, c0);
            c1 = mfma16(G[cur][0],      w3, c1);
            c0 = mfma16(G[cur][4 + br], w4, c0);
            c1 = mfma16(G[cur][4 + br], w5, c1);
            float a0 = A_[br][0], b0 = B_[br][0];
            float a1 = A_[br][1], b1 = B_[br][1];
            #pragma unroll
            for (int r = 0; r < 4; ++r) {
                float e0 = __builtin_amdgcn_exp2f(__builtin_fmaf(c0[r], a0, b0));
                float e1 = __builtin_amdgcn_exp2f(__builtin_fmaf(c1[r], a1, b1));
                acc0[r] += __builtin_amdgcn_rcpf(1.0f + e0);
                acc1[r] += __builtin_amdgcn_rcpf(1.0f + e1);
            }
        }

        #pragma unroll
        for (int r = 0; r < 4; ++r) {
            int vrow = base + quad * 4 + r;
            f32x2 ov = { acc0[r] * fv[r][0], acc1[r] * fv[r][1] };
            __builtin_nontemporal_store(ov, (f32x2*)(out + vrow * 32 + 2 * n));
        }
    }
}

// --------------------- legacy path (proven R3 kernel) ---------------------
__global__ __launch_bounds__(256) void recon_legacy(
    const float*          __restrict__ feat,
    const int*            __restrict__ nprev,
    const int*            __restrict__ nnext,
    const unsigned short* __restrict__ wsW,
    const float*          __restrict__ wsA,
    const float*          __restrict__ wsB,
    float*                __restrict__ out)
{
    const int lane = threadIdx.x & 63;
    const int n    = lane & 15;
    const int quad = lane >> 4;

    int b   = blockIdx.x;
    int per = NBLOCKS2 / 8;
    int bs  = (b < per * 8) ? ((b & 7) * per + (b >> 3)) : b;
    int wv  = bs * WPB + (threadIdx.x >> 6);

    const int t0 = wv * TPW2;
    if (t0 >= NTILES) return;

    bf16x8 Bf[18];
    #pragma unroll
    for (int f = 0; f < 18; ++f)
        Bf[f] = __builtin_bit_cast(bf16x8, *(const u16x8*)(wsW + (f * 64 + lane) * 8));

    f32x2 A_[3], B_[3];
    #pragma unroll
    for (int br = 0; br < 3; ++br) {
        A_[br] = *(const f32x2*)(wsA + br * 32 + 2 * n);
        B_[br] = *(const f32x2*)(wsB + br * 32 + 2 * n);
    }

    int ip[3], inx[3];
    {
        int row0 = t0 * 16 + n;
        #pragma unroll
        for (int a = 0; a < 3; ++a) {
            ip[a]  = nprev[a * NVOX + row0];
            inx[a] = nnext[a * NVOX + row0];
        }
    }

    #pragma unroll 1
    for (int tt = 0; tt < TPW2; ++tt) {
        int tile = t0 + tt;
        if (tile >= NTILES) break;
        int base = tile * 16;
        int row  = base + n;

        const f32x4* ps = (const f32x4*)(feat + row * 32 + quad * 8);
        f32x4 s_lo = ps[0], s_hi = ps[1];
        f32x4 p_lo[3], p_hi[3], n_lo[3], n_hi[3];
        #pragma unroll
        for (int a = 0; a < 3; ++a) {
            p_lo[a] = (f32x4){0.f, 0.f, 0.f, 0.f}; p_hi[a] = p_lo[a];
            n_lo[a] = p_lo[a];                     n_hi[a] = p_lo[a];
            if (ip[a] >= 0) {
                const f32x4* pp = (const f32x4*)(feat + ip[a] * 32 + quad * 8);
                p_lo[a] = pp[0]; p_hi[a] = pp[1];
            }
            if (inx[a] >= 0) {
                const f32x4* pn = (const f32x4*)(feat + inx[a] * 32 + quad * 8);
                n_lo[a] = pn[0]; n_hi[a] = pn[1];
            }
        }

        int ipn[3], inn[3];
        if (tt + 1 < TPW2 && tile + 1 < NTILES) {
            int nrow = row + 16;
            #pragma unroll
            for (int a = 0; a < 3; ++a) {
                ipn[a] = nprev[a * NVOX + nrow];
                inn[a] = nnext[a * NVOX + nrow];
            }
        } else {
            #pragma unroll
            for (int a = 0; a < 3; ++a) { ipn[a] = -1; inn[a] = -1; }
        }

        bf16x8 Aself = cvt_frag(s_lo, s_hi);
        bf16x8 Ap[3], An[3];
        #pragma unroll
        for (int a = 0; a < 3; ++a) {
            Ap[a] = cvt_frag(p_lo[a], p_hi[a]);
            An[a] = cvt_frag(n_lo[a], n_hi[a]);
        }

        f32x4 acc0 = {0.f, 0.f, 0.f, 0.f}, acc1 = {0.f, 0.f, 0.f, 0.f};
        #pragma unroll
        for (int br = 0; br < 3; ++br) {
            f32x4 c0 = {0.f, 0.f, 0.f, 0.f}, c1 = {0.f, 0.f, 0.f, 0.f};
            c0 = __builtin_amdgcn_mfma_f32_16x16x32_bf16(Ap[br], Bf[br*6 + 0], c0, 0, 0, 0);
            c1 = __builtin_amdgcn_mfma_f32_16x16x32_bf16(Ap[br], Bf[br*6 + 1], c1, 0, 0, 0);
            c0 = __builtin_amdgcn_mfma_f32_16x16x32_bf16(Aself,  Bf[br*6 + 2], c0, 0, 0, 0);
            c1 = __builtin_amdgcn_mfma_f32_16x16x32_bf16(Aself,  Bf[br*6 + 3], c1, 0, 0, 0);
            c0 = __builtin_amdgcn_mfma_f32_16x16x32_bf16(An[br], Bf[br*6 + 4], c0, 0, 0, 0);
            c1 = __builtin_amdgcn_mfma_f32_16x16x32_bf16(An[br], Bf[br*6 + 5], c1, 0, 0, 0);
            float a0 = A_[br][0], b0 = B_[br][0], a1 = A_[br][1], b1 = B_[br][1];
            #pragma unroll
            for (int r = 0; r < 4; ++r) {
                float e0 = __builtin_amdgcn_exp2f(__builtin_fmaf(c0[r], a0, b0));
                float e1 = __builtin_amdgcn_exp2f(__builtin_fmaf(c1[r], a1, b1));
                acc0[r] += __builtin_amdgcn_rcpf(1.0f + e0);
                acc1[r] += __builtin_amdgcn_rcpf(1.0f + e1);
            }
        }

        #pragma unroll
        for (int r = 0; r < 4; ++r) {
            int vrow = base + quad * 4 + r;
            f32x2 fv = *(const f32x2*)(feat + vrow * 32 + 2 * n);
            f32x2 ov = { acc0[r] * fv[0], acc1[r] * fv[1] };
            *(f32x2*)(out + vrow * 32 + 2 * n) = ov;
        }

        #pragma unroll
        for (int a = 0; a < 3; ++a) { ip[a] = ipn[a]; inx[a] = inn[a]; }
    }
}

extern "C" void kernel_launch(void* const* d_in, const int* in_sizes, int n_in,
                              void* d_out, int out_size, void* d_ws, size_t ws_size,
                              hipStream_t stream) {
    const float* feat  = (const float*)d_in[0];
    const int*   nprev = (const int*)d_in[1];
    const int*   nnext = (const int*)d_in[2];
    const float* Wt    = (const float*)d_in[3];
    const float* gma   = (const float*)d_in[4];
    const float* bta   = (const float*)d_in[5];
    const float* mea   = (const float*)d_in[6];
    const float* var   = (const float*)d_in[7];
    float*       o     = (float*)d_out;

    if (ws_size >= WS_NEED) {
        unsigned short* fb  = (unsigned short*)d_ws;
        unsigned short* wsW = (unsigned short*)((char*)d_ws + FB_BYTES);
        float* wsA = (float*)((char*)d_ws + FB_BYTES + 18432);
        float* wsB = wsA + 96;
        float* wsZ = wsB + 96;                     // 128-B zero row
        prep_all<<<PREPALL_BLK, 256, 0, stream>>>(
            feat, fb, Wt, gma, bta, mea, var, wsW, wsA, wsB, wsZ);
        recon_bf16<<<NBLOCKSF, 256, 0, stream>>>(feat, nprev, nnext,
            (const char*)d_ws, wsW, wsA, wsB, o);
    } else {
        unsigned short* wsW = (unsigned short*)d_ws;
        float* wsA = (float*)((char*)d_ws + WS_WELEMS * 2);
        float* wsB = wsA + 96;
        prep_kernel<<<(PREP_TAIL + 255) / 256, 256, 0, stream>>>(
            Wt, gma, bta, mea, var, wsW, wsA, wsB);
        recon_legacy<<<NBLOCKS2, 256, 0, stream>>>(feat, nprev, nnext,
                                                   wsW, wsA, wsB, o);
    }
}

// Round 4
// 297.379 us; speedup vs baseline: 1.0286x; 1.0286x over previous
//
#include <hip/hip_runtime.h>
#include <stdint.h>

// ReconBlock: 3-axis 3-tap submanifold conv (gathered neighbors) + BN(inference)
// + sigmoid per branch, branches summed, gated by input features.
//
// R6 (resubmit after infra failure): revert R5 regressions (TPW back to 4, no
// nontemporal on index path). New: wave-wide index preload (6 coalesced 256B
// loads/wave for ALL tiles, per-tile indices via __shfl from registers) +
// depth-2 gather ring (G[3], 14 outstanding gathers/wave) to cover HBM-miss
// latency. Core structure unchanged: bf16 feature cache -> MFMA A-fragments,
// LDS weights behind opaque offset, zero-row cndmask for invalid neighbors,
// XCD swizzle, fused prep (feature cvt + weight fragments + BN fold).
// Legacy fallback when ws is small.

typedef __attribute__((ext_vector_type(8))) __bf16 bf16x8;
typedef __attribute__((ext_vector_type(8))) unsigned short u16x8;
typedef __attribute__((ext_vector_type(4))) float f32x4;
typedef __attribute__((ext_vector_type(2))) float f32x2;

constexpr int NVOX    = 1000000;
constexpr int NTILES  = NVOX / 16;                  // 62500
constexpr int WPB     = 4;                          // waves per block
constexpr float LOG2E = 1.4426950408889634f;

// ---- fast path geometry (bf16 feature cache) ----
constexpr int TPWF     = 4;                         // tiles per wave (=64 rows)
constexpr int NWAVESF  = NTILES / TPWF;             // 15625 (exact)
constexpr int NBLOCKSF = (NWAVESF + WPB - 1) / WPB; // 3907

// ---- legacy path geometry ----
constexpr int TPW2     = 2;
constexpr int NWAVES2  = (NTILES + TPW2 - 1) / TPW2;   // 31250
constexpr int NBLOCKS2 = (NWAVES2 + WPB - 1) / WPB;    // 7813

// ws layout (fast): [fb bf16 64e6 B][wsW 18432][wsA 384][wsB 384][zeros 128]
// ws layout (legacy): [wsW 18432][wsA 384][wsB 384]
constexpr int    WS_WELEMS = 18 * 64 * 8;           // 9216 bf16 elems
constexpr size_t FB_BYTES  = (size_t)NVOX * 64;     // 64,000,000
constexpr unsigned ZOFF    = (unsigned)(FB_BYTES + 18432 + 768); // zero row
constexpr size_t WS_NEED   = FB_BYTES + 18432 + 768 + 128;

// fused prep: first CVT_THREADS threads convert features (16 floats each),
// the tail does weight-fragment / BN-constant / zero-row prep.
constexpr int CVT_THREADS = NVOX * 32 / 16;         // 2,000,000
constexpr int PREP_TAIL   = WS_WELEMS + 96 + 32;    // 9344
constexpr int PREPALL_BLK = (CVT_THREADS + PREP_TAIL + 255) / 256; // 7849

__device__ __forceinline__ unsigned pack_bf(float a, float b) {
    union { float f; unsigned u; } ca, cb; ca.f = a; cb.f = b;
    // d = hi16(a+0x8000) | hi16(b+0x8000)<<16  (one v_perm)
    return __builtin_amdgcn_perm(cb.u + 0x8000u, ca.u + 0x8000u, 0x07060302u);
}

__device__ __forceinline__ void prep_tail_work(
    int t, const float* __restrict__ Wt,
    const float* __restrict__ gma, const float* __restrict__ bta,
    const float* __restrict__ mea, const float* __restrict__ var,
    unsigned short* __restrict__ wsW, float* __restrict__ wsA,
    float* __restrict__ wsB, float* __restrict__ wsZ)
{
    if (t < WS_WELEMS) {
        int f    = t >> 9;            // fragment id = (br*3+tap)*2+h
        int rem  = t & 511;
        int lane = rem >> 3;
        int j    = rem & 7;
        int br = f / 6, tap = (f >> 1) % 3, h = f & 1;
        int n = lane & 15, quad = lane >> 4;
        // B[k=quad*8+j][col]; col interleave: half h = original channel 2n+h
        float w = Wt[((br * 3 + tap) * 32 + quad * 8 + j) * 32 + 2 * n + h];
        union { float f; unsigned u; } c; c.f = w;
        wsW[(f * 64 + lane) * 8 + j] = (unsigned short)((c.u + 0x8000u) >> 16);
    } else if (t < WS_WELEMS + 96) {
        int i = t - WS_WELEMS;        // br*32 + c
        float s = gma[i] * __frsqrt_rn(var[i] + 1e-5f);
        wsA[i] = -s * LOG2E;
        wsB[i] = (mea[i] * s - bta[i]) * LOG2E;
    } else if (wsZ != nullptr && t < WS_WELEMS + 96 + 32) {
        wsZ[t - WS_WELEMS - 96] = 0.0f;
    }
}

// fused: feature fp32->bf16 conversion (same +0x8000 rounding as the MFMA
// fragment packing, numerics identical to R3/R4) + weight/BN/zero prep.
__global__ __launch_bounds__(256) void prep_all(
    const float* __restrict__ feat, unsigned short* __restrict__ fb,
    const float* __restrict__ Wt,
    const float* __restrict__ gma, const float* __restrict__ bta,
    const float* __restrict__ mea, const float* __restrict__ var,
    unsigned short* __restrict__ wsW, float* __restrict__ wsA,
    float* __restrict__ wsB, float* __restrict__ wsZ)
{
    int tid = blockIdx.x * 256 + threadIdx.x;
    if (tid < CVT_THREADS) {
        const f32x4* p = (const f32x4*)(feat + (size_t)tid * 16);
        f32x4 v0 = p[0], v1 = p[1], v2 = p[2], v3 = p[3];
        union { unsigned u[8]; u16x8 v[2]; } r;
        r.u[0] = pack_bf(v0[0], v0[1]); r.u[1] = pack_bf(v0[2], v0[3]);
        r.u[2] = pack_bf(v1[0], v1[1]); r.u[3] = pack_bf(v1[2], v1[3]);
        r.u[4] = pack_bf(v2[0], v2[1]); r.u[5] = pack_bf(v2[2], v2[3]);
        r.u[6] = pack_bf(v3[0], v3[1]); r.u[7] = pack_bf(v3[2], v3[3]);
        u16x8* q = (u16x8*)(fb + (size_t)tid * 16);
        q[0] = r.v[0]; q[1] = r.v[1];
    } else {
        prep_tail_work(tid - CVT_THREADS, Wt, gma, bta, mea, var,
                       wsW, wsA, wsB, wsZ);
    }
}

// legacy-path prep (no feature cache)
__global__ __launch_bounds__(256) void prep_kernel(
    const float* __restrict__ Wt,
    const float* __restrict__ gma, const float* __restrict__ bta,
    const float* __restrict__ mea, const float* __restrict__ var,
    unsigned short* __restrict__ wsW, float* __restrict__ wsA,
    float* __restrict__ wsB)
{
    int tid = blockIdx.x * 256 + threadIdx.x;
    prep_tail_work(tid, Wt, gma, bta, mea, var, wsW, wsA, wsB, nullptr);
}

__device__ __forceinline__ bf16x8 cvt_frag(f32x4 lo, f32x4 hi) {
    union { unsigned u[4]; bf16x8 v; } r;
    r.u[0] = pack_bf(lo[0], lo[1]); r.u[1] = pack_bf(lo[2], lo[3]);
    r.u[2] = pack_bf(hi[0], hi[1]); r.u[3] = pack_bf(hi[2], hi[3]);
    return r.v;
}

__device__ __forceinline__ f32x4 mfma16(u16x8 a, bf16x8 b, f32x4 c) {
    return __builtin_amdgcn_mfma_f32_16x16x32_bf16(
        __builtin_bit_cast(bf16x8, a), b, c, 0, 0, 0);
}

// ------------------------------ fast path ------------------------------
__global__ __launch_bounds__(256) void recon_bf16(
    const float* __restrict__ feat,   // [N][32] fp32 (gate only)
    const int*   __restrict__ nprev,  // [3][N]
    const int*   __restrict__ nnext,  // [3][N]
    const char*  __restrict__ fbc,    // ws base: bf16 features at offset 0
    const unsigned short* __restrict__ wsW,
    const float* __restrict__ wsA,
    const float* __restrict__ wsB,
    float*       __restrict__ out)    // [N][32]
{
    __shared__ unsigned short smem[WS_WELEMS];     // 18 KB weight fragments
    {
        const u16x8* s = (const u16x8*)wsW;
        u16x8* d = (u16x8*)smem;
        #pragma unroll
        for (int i = 0; i < 5; ++i) {
            int k = (int)threadIdx.x + i * 256;
            if (k < 18 * 64) d[k] = s[k];
        }
    }
    __syncthreads();

    const int lane = threadIdx.x & 63;
    const int n    = lane & 15;       // lane owns out channels 2n, 2n+1
    const int quad = lane >> 4;
    const unsigned qo = (unsigned)quad * 16u;

    // XCD-aware swizzle: contiguous 1/8th of voxel range per XCD
    int b   = blockIdx.x;
    int per = NBLOCKSF / 8;
    int bs  = (b < per * 8) ? ((b & 7) * per + (b >> 3)) : b;
    int wv  = bs * WPB + (threadIdx.x >> 6);
    if (wv >= NWAVESF) return;
    const int t0 = wv * TPWF;

    // folded BN consts for this lane's channels (2n, 2n+1)
    f32x2 A_[3], B_[3];
    #pragma unroll
    for (int br = 0; br < 3; ++br) {
        A_[br] = *(const f32x2*)(wsA + br * 32 + 2 * n);
        B_[br] = *(const f32x2*)(wsB + br * 32 + 2 * n);
    }

    // opaque per-tile LDS byte offset (defeats LICM of weight ds_reads)
    unsigned lbase = (unsigned)lane * 16u;

    // ---- wave-wide index preload: lane l holds the idx for row t0*16+l.
    // One fully-coalesced 256B load per stream covers ALL TPWF tiles.
    int pAll[3], nAll[3];
    {
        int r64 = t0 * 16 + lane;
        #pragma unroll
        for (int a = 0; a < 3; ++a) {
            pAll[a] = nprev[a * NVOX + r64];
            nAll[a] = nnext[a * NVOX + r64];
        }
    }

    // ---- depth-2 gather ring: [0]=self, [1..3]=prev a, [4..6]=next a
    u16x8 G[3][7];
    #pragma unroll
    for (int tt = 0; tt < 2; ++tt) {
        int row = t0 * 16 + tt * 16 + n;
        G[tt][0] = *(const u16x8*)(fbc + (unsigned)row * 64u + qo);
        #pragma unroll
        for (int a = 0; a < 3; ++a) {
            int ip = __shfl(pAll[a], tt * 16 + n, 64);
            int in_ = __shfl(nAll[a], tt * 16 + n, 64);
            unsigned op = ip >= 0 ? (unsigned)ip * 64u : ZOFF;
            unsigned on = in_ >= 0 ? (unsigned)in_ * 64u : ZOFF;
            G[tt][1 + a] = *(const u16x8*)(fbc + op + qo);
            G[tt][4 + a] = *(const u16x8*)(fbc + on + qo);
        }
    }

    #pragma unroll
    for (int tt = 0; tt < TPWF; ++tt) {
        const int cur  = tt % 3;
        const int pre  = (tt + 2) % 3;
        const int base = (t0 + tt) * 16;

        // gate loads early (fp32, read-once -> nontemporal; hidden under MFMA)
        f32x2 fv[4];
        #pragma unroll
        for (int r = 0; r < 4; ++r)
            fv[r] = __builtin_nontemporal_load(
                (const f32x2*)(feat + (base + quad * 4 + r) * 32 + 2 * n));

        // issue gathers two tiles ahead: ~2 tiles of compute in flight above
        if (tt + 2 < TPWF) {
            int rown = base + 32 + n;
            G[pre][0] = *(const u16x8*)(fbc + (unsigned)rown * 64u + qo);
            #pragma unroll
            for (int a = 0; a < 3; ++a) {
                int ip = __shfl(pAll[a], (tt + 2) * 16 + n, 64);
                int in_ = __shfl(nAll[a], (tt + 2) * 16 + n, 64);
                unsigned op = ip >= 0 ? (unsigned)ip * 64u : ZOFF;
                unsigned on = in_ >= 0 ? (unsigned)in_ * 64u : ZOFF;
                G[pre][1 + a] = *(const u16x8*)(fbc + op + qo);
                G[pre][4 + a] = *(const u16x8*)(fbc + on + qo);
            }
        }

        asm volatile("" : "+v"(lbase));            // loop-variant LDS base
        const char* sb = (const char*)smem + lbase;

        f32x4 acc0 = {0.f, 0.f, 0.f, 0.f}, acc1 = {0.f, 0.f, 0.f, 0.f};
        #pragma unroll
        for (int br = 0; br < 3; ++br) {
            bf16x8 w0 = *(const bf16x8*)(sb + (br * 6 + 0) * 1024);
            bf16x8 w1 = *(const bf16x8*)(sb + (br * 6 + 1) * 1024);
            bf16x8 w2 = *(const bf16x8*)(sb + (br * 6 + 2) * 1024);
            bf16x8 w3 = *(const bf16x8*)(sb + (br * 6 + 3) * 1024);
            bf16x8 w4 = *(const bf16x8*)(sb + (br * 6 + 4) * 1024);
            bf16x8 w5 = *(const bf16x8*)(sb + (br * 6 + 5) * 1024);
            f32x4 c0 = {0.f, 0.f, 0.f, 0.f}, c1 = {0.f, 0.f, 0.f, 0.f};
            c0 = mfma16(G[cur][1 + br], w0, c0);
            c1 = mfma16(G[cur][1 + br], w1, c1);
            c0 = mfma16(G[cur][0],      w2, c0);
            c1 = mfma16(G[cur][0],      w3, c1);
            c0 = mfma16(G[cur][4 + br], w4, c0);
            c1 = mfma16(G[cur][4 + br], w5, c1);
            float a0 = A_[br][0], b0 = B_[br][0];
            float a1 = A_[br][1], b1 = B_[br][1];
            #pragma unroll
            for (int r = 0; r < 4; ++r) {
                float e0 = __builtin_amdgcn_exp2f(__builtin_fmaf(c0[r], a0, b0));
                float e1 = __builtin_amdgcn_exp2f(__builtin_fmaf(c1[r], a1, b1));
                acc0[r] += __builtin_amdgcn_rcpf(1.0f + e0);
                acc1[r] += __builtin_amdgcn_rcpf(1.0f + e1);
            }
        }

        #pragma unroll
        for (int r = 0; r < 4; ++r) {
            int vrow = base + quad * 4 + r;
            f32x2 ov = { acc0[r] * fv[r][0], acc1[r] * fv[r][1] };
            __builtin_nontemporal_store(ov, (f32x2*)(out + vrow * 32 + 2 * n));
        }
    }
}

// --------------------- legacy path (proven R3 kernel) ---------------------
__global__ __launch_bounds__(256) void recon_legacy(
    const float*          __restrict__ feat,
    const int*            __restrict__ nprev,
    const int*            __restrict__ nnext,
    const unsigned short* __restrict__ wsW,
    const float*          __restrict__ wsA,
    const float*          __restrict__ wsB,
    float*                __restrict__ out)
{
    const int lane = threadIdx.x & 63;
    const int n    = lane & 15;
    const int quad = lane >> 4;

    int b   = blockIdx.x;
    int per = NBLOCKS2 / 8;
    int bs  = (b < per * 8) ? ((b & 7) * per + (b >> 3)) : b;
    int wv  = bs * WPB + (threadIdx.x >> 6);

    const int t0 = wv * TPW2;
    if (t0 >= NTILES) return;

    bf16x8 Bf[18];
    #pragma unroll
    for (int f = 0; f < 18; ++f)
        Bf[f] = __builtin_bit_cast(bf16x8, *(const u16x8*)(wsW + (f * 64 + lane) * 8));

    f32x2 A_[3], B_[3];
    #pragma unroll
    for (int br = 0; br < 3; ++br) {
        A_[br] = *(const f32x2*)(wsA + br * 32 + 2 * n);
        B_[br] = *(const f32x2*)(wsB + br * 32 + 2 * n);
    }

    int ip[3], inx[3];
    {
        int row0 = t0 * 16 + n;
        #pragma unroll
        for (int a = 0; a < 3; ++a) {
            ip[a]  = nprev[a * NVOX + row0];
            inx[a] = nnext[a * NVOX + row0];
        }
    }

    #pragma unroll 1
    for (int tt = 0; tt < TPW2; ++tt) {
        int tile = t0 + tt;
        if (tile >= NTILES) break;
        int base = tile * 16;
        int row  = base + n;

        const f32x4* ps = (const f32x4*)(feat + row * 32 + quad * 8);
        f32x4 s_lo = ps[0], s_hi = ps[1];
        f32x4 p_lo[3], p_hi[3], n_lo[3], n_hi[3];
        #pragma unroll
        for (int a = 0; a < 3; ++a) {
            p_lo[a] = (f32x4){0.f, 0.f, 0.f, 0.f}; p_hi[a] = p_lo[a];
            n_lo[a] = p_lo[a];                     n_hi[a] = p_lo[a];
            if (ip[a] >= 0) {
                const f32x4* pp = (const f32x4*)(feat + ip[a] * 32 + quad * 8);
                p_lo[a] = pp[0]; p_hi[a] = pp[1];
            }
            if (inx[a] >= 0) {
                const f32x4* pn = (const f32x4*)(feat + inx[a] * 32 + quad * 8);
                n_lo[a] = pn[0]; n_hi[a] = pn[1];
            }
        }

        int ipn[3], inn[3];
        if (tt + 1 < TPW2 && tile + 1 < NTILES) {
            int nrow = row + 16;
            #pragma unroll
            for (int a = 0; a < 3; ++a) {
                ipn[a] = nprev[a * NVOX + nrow];
                inn[a] = nnext[a * NVOX + nrow];
            }
        } else {
            #pragma unroll
            for (int a = 0; a < 3; ++a) { ipn[a] = -1; inn[a] = -1; }
        }

        bf16x8 Aself = cvt_frag(s_lo, s_hi);
        bf16x8 Ap[3], An[3];
        #pragma unroll
        for (int a = 0; a < 3; ++a) {
            Ap[a] = cvt_frag(p_lo[a], p_hi[a]);
            An[a] = cvt_frag(n_lo[a], n_hi[a]);
        }

        f32x4 acc0 = {0.f, 0.f, 0.f, 0.f}, acc1 = {0.f, 0.f, 0.f, 0.f};
        #pragma unroll
        for (int br = 0; br < 3; ++br) {
            f32x4 c0 = {0.f, 0.f, 0.f, 0.f}, c1 = {0.f, 0.f, 0.f, 0.f};
            c0 = __builtin_amdgcn_mfma_f32_16x16x32_bf16(Ap[br], Bf[br*6 + 0], c0, 0, 0, 0);
            c1 = __builtin_amdgcn_mfma_f32_16x16x32_bf16(Ap[br], Bf[br*6 + 1], c1, 0, 0, 0);
            c0 = __builtin_amdgcn_mfma_f32_16x16x32_bf16(Aself,  Bf[br*6 + 2], c0, 0, 0, 0);
            c1 = __builtin_amdgcn_mfma_f32_16x16x32_bf16(Aself,  Bf[br*6 + 3], c1, 0, 0, 0);
            c0 = __builtin_amdgcn_mfma_f32_16x16x32_bf16(An[br], Bf[br*6 + 4], c0, 0, 0, 0);
            c1 = __builtin_amdgcn_mfma_f32_16x16x32_bf16(An[br], Bf[br*6 + 5], c1, 0, 0, 0);
            float a0 = A_[br][0], b0 = B_[br][0], a1 = A_[br][1], b1 = B_[br][1];
            #pragma unroll
            for (int r = 0; r < 4; ++r) {
                float e0 = __builtin_amdgcn_exp2f(__builtin_fmaf(c0[r], a0, b0));
                float e1 = __builtin_amdgcn_exp2f(__builtin_fmaf(c1[r], a1, b1));
                acc0[r] += __builtin_amdgcn_rcpf(1.0f + e0);
                acc1[r] += __builtin_amdgcn_rcpf(1.0f + e1);
            }
        }

        #pragma unroll
        for (int r = 0; r < 4; ++r) {
            int vrow = base + quad * 4 + r;
            f32x2 fv = *(const f32x2*)(feat + vrow * 32 + 2 * n);
            f32x2 ov = { acc0[r] * fv[0], acc1[r] * fv[1] };
            *(f32x2*)(out + vrow * 32 + 2 * n) = ov;
        }

        #pragma unroll
        for (int a = 0; a < 3; ++a) { ip[a] = ipn[a]; inx[a] = inn[a]; }
    }
}

extern "C" void kernel_launch(void* const* d_in, const int* in_sizes, int n_in,
                              void* d_out, int out_size, void* d_ws, size_t ws_size,
                              hipStream_t stream) {
    const float* feat  = (const float*)d_in[0];
    const int*   nprev = (const int*)d_in[1];
    const int*   nnext = (const int*)d_in[2];
    const float* Wt    = (const float*)d_in[3];
    const float* gma   = (const float*)d_in[4];
    const float* bta   = (const float*)d_in[5];
    const float* mea   = (const float*)d_in[6];
    const float* var   = (const float*)d_in[7];
    float*       o     = (float*)d_out;

    if (ws_size >= WS_NEED) {
        unsigned short* fb  = (unsigned short*)d_ws;
        unsigned short* wsW = (unsigned short*)((char*)d_ws + FB_BYTES);
        float* wsA = (float*)((char*)d_ws + FB_BYTES + 18432);
        float* wsB = wsA + 96;
        float* wsZ = wsB + 96;                     // 128-B zero row
        prep_all<<<PREPALL_BLK, 256, 0, stream>>>(
            feat, fb, Wt, gma, bta, mea, var, wsW, wsA, wsB, wsZ);
        recon_bf16<<<NBLOCKSF, 256, 0, stream>>>(feat, nprev, nnext,
            (const char*)d_ws, wsW, wsA, wsB, o);
    } else {
        unsigned short* wsW = (unsigned short*)d_ws;
        float* wsA = (float*)((char*)d_ws + WS_WELEMS * 2);
        float* wsB = wsA + 96;
        prep_kernel<<<(PREP_TAIL + 255) / 256, 256, 0, stream>>>(
            Wt, gma, bta, mea, var, wsW, wsA, wsB);
        recon_legacy<<<NBLOCKS2, 256, 0, stream>>>(feat, nprev, nnext,
                                                   wsW, wsA, wsB, o);
    }
}